// Round 1
// baseline (1208.233 us; speedup 1.0000x reference)
//
#include <hip/hip_runtime.h>
#include <math.h>

// Shapes (fixed): B=4, C=256, H=W=64, N=4096, 4C=1024, c8=32, r=16.

// ---------------------------------------------------------------------------
// K1/K5: per-(b,c) plane -> block-mean pyramid (+ feats in mode 0, x2 in mode 1)
// mode 0: plane = x;             writes bm2/bm4/bm8 + 5 feats
// mode 1: plane = x*g[c]*spg;    writes x2 + bm2b/bm4b/bm8b
// ---------------------------------------------------------------------------
__global__ __launch_bounds__(256) void k_pyramid(
    const float* __restrict__ xin, const float* __restrict__ gch,
    const float* __restrict__ spg, float* __restrict__ x2out,
    float* __restrict__ bm2, float* __restrict__ bm4, float* __restrict__ bm8,
    float* __restrict__ featA, float* __restrict__ fm1, float* __restrict__ fm2,
    float* __restrict__ fm4, float* __restrict__ fm8, int mode)
{
    __shared__ float sx[4096];
    __shared__ float s2[1024];
    __shared__ float s4[256];
    __shared__ float red[256];
    const int bc = blockIdx.x;
    const int b = bc >> 8;
    const int t = threadIdx.x;
    const float* xp = xin + (size_t)bc * 4096;
    float gc = 1.f;
    if (mode == 1) gc = gch[bc];
    float sum = 0.f, mx = -1e30f;
    for (int r = 0; r < 4; r++) {
        int i4 = t + 256 * r;
        float4 v = ((const float4*)xp)[i4];
        if (mode == 1) {
            float4 sg = ((const float4*)(spg + (size_t)b * 4096))[i4];
            v.x *= gc * sg.x; v.y *= gc * sg.y; v.z *= gc * sg.z; v.w *= gc * sg.w;
            ((float4*)(x2out + (size_t)bc * 4096))[i4] = v;
        } else {
            sum += v.x + v.y + v.z + v.w;
            mx = fmaxf(mx, fmaxf(fmaxf(v.x, v.y), fmaxf(v.z, v.w)));
        }
        ((float4*)sx)[i4] = v;
    }
    __syncthreads();
    float mx2 = -1e30f;
    for (int r = 0; r < 4; r++) {
        int i = t + 256 * r;                       // 0..1023: (r2,c2) in 32x32
        int r2 = i >> 5, c2 = i & 31;
        int p0 = 128 * r2 + 2 * c2;
        float v = 0.25f * (sx[p0] + sx[p0 + 1] + sx[p0 + 64] + sx[p0 + 65]);
        s2[i] = v;
        bm2[(size_t)bc * 1024 + i] = v;
        mx2 = fmaxf(mx2, v);
    }
    __syncthreads();
    float mx4;
    {
        int r4 = t >> 4, c4 = t & 15;              // 16x16
        int p0 = 64 * r4 + 2 * c4;
        float v = 0.25f * (s2[p0] + s2[p0 + 1] + s2[p0 + 32] + s2[p0 + 33]);
        s4[t] = v;
        bm4[(size_t)bc * 256 + t] = v;
        mx4 = v;
    }
    __syncthreads();
    float mx8 = -1e30f;
    if (t < 64) {
        int r8 = t >> 3, c8 = t & 7;               // 8x8
        int p0 = 32 * r8 + 2 * c8;
        float v = 0.25f * (s4[p0] + s4[p0 + 1] + s4[p0 + 16] + s4[p0 + 17]);
        bm8[(size_t)bc * 64 + t] = v;
        mx8 = v;
    }
    if (mode == 0) {
        red[t] = sum; __syncthreads();
        for (int s = 128; s > 0; s >>= 1) { if (t < s) red[t] += red[t + s]; __syncthreads(); }
        if (t == 0) featA[bc] = red[0] * (1.f / 4096.f);
        __syncthreads();
        red[t] = mx; __syncthreads();
        for (int s = 128; s > 0; s >>= 1) { if (t < s) red[t] = fmaxf(red[t], red[t + s]); __syncthreads(); }
        if (t == 0) fm1[bc] = red[0];
        __syncthreads();
        red[t] = mx2; __syncthreads();
        for (int s = 128; s > 0; s >>= 1) { if (t < s) red[t] = fmaxf(red[t], red[t + s]); __syncthreads(); }
        if (t == 0) fm2[bc] = red[0];
        __syncthreads();
        red[t] = mx4; __syncthreads();
        for (int s = 128; s > 0; s >>= 1) { if (t < s) red[t] = fmaxf(red[t], red[t + s]); __syncthreads(); }
        if (t == 0) fm4[bc] = red[0];
        __syncthreads();
        red[t] = mx8; __syncthreads();
        for (int s = 128; s > 0; s >>= 1) { if (t < s) red[t] = fmaxf(red[t], red[t + s]); __syncthreads(); }
        if (t == 0) fm8[bc] = red[0];
    }
}

// ---------------------------------------------------------------------------
// K2: channel-gate MLP.  att = 4*MLP(featA) + MLP(fm1)+MLP(fm2)+MLP(fm4)+MLP(fm8)
//     (b2 enters 8x, b1 inside each relu). g = sigmoid(att). One block per b.
// ---------------------------------------------------------------------------
__global__ __launch_bounds__(256) void k2_gate(
    const float* __restrict__ featA, const float* __restrict__ fm1,
    const float* __restrict__ fm2, const float* __restrict__ fm4, const float* __restrict__ fm8,
    const float* __restrict__ W1, const float* __restrict__ b1,
    const float* __restrict__ W2, const float* __restrict__ b2,
    float* __restrict__ g)
{
    __shared__ float sf[5][256];
    __shared__ float sh[5][16];
    __shared__ float hs[16];
    const int b = blockIdx.x, t = threadIdx.x;
    sf[0][t] = featA[b * 256 + t];
    sf[1][t] = fm1[b * 256 + t];
    sf[2][t] = fm2[b * 256 + t];
    sf[3][t] = fm4[b * 256 + t];
    sf[4][t] = fm8[b * 256 + t];
    __syncthreads();
    if (t < 80) {
        int f = t / 16, j = t % 16;
        float a = b1[j];
        for (int c = 0; c < 256; c++) a += sf[f][c] * W1[c * 16 + j];
        sh[f][j] = fmaxf(a, 0.f);
    }
    __syncthreads();
    if (t < 16) hs[t] = 4.f * sh[0][t] + sh[1][t] + sh[2][t] + sh[3][t] + sh[4][t];
    __syncthreads();
    float a = 8.f * b2[t];
    for (int j = 0; j < 16; j++) a += hs[j] * W2[j * 256 + t];
    g[b * 256 + t] = 1.f / (1.f + __expf(-a));
}

// ---------------------------------------------------------------------------
// K3: spatial-gate input: per pixel max & mean over the 4C multiscale channels
//     of x1 = g[c]*x (block-means of x1 = g[c]*block-means of x).
// ---------------------------------------------------------------------------
__global__ __launch_bounds__(256) void k3_comp(
    const float* __restrict__ x, const float* __restrict__ bm2,
    const float* __restrict__ bm4, const float* __restrict__ bm8,
    const float* __restrict__ g, float* __restrict__ comp)
{
    __shared__ float sg[256];
    const int b = blockIdx.x >> 4;
    const int pix = ((blockIdx.x & 15) << 8) + threadIdx.x;
    sg[threadIdx.x] = g[(b << 8) + threadIdx.x];
    __syncthreads();
    const int h = pix >> 6, w = pix & 63;
    const int i2 = ((h >> 1) << 5) + (w >> 1);
    const int i4 = ((h >> 2) << 4) + (w >> 2);
    const int i8 = ((h >> 3) << 3) + (w >> 3);
    const float* xb = x + ((size_t)b << 8) * 4096;
    const float* p2 = bm2 + ((size_t)b << 8) * 1024;
    const float* p4 = bm4 + ((size_t)b << 8) * 256;
    const float* p8 = bm8 + ((size_t)b << 8) * 64;
    float mx = -1e30f, sm = 0.f;
    for (int c = 0; c < 256; c++) {
        float gc = sg[c];
        float xv = xb[(size_t)c * 4096 + pix] * gc;
        float v2 = p2[c * 1024 + i2] * gc;
        float v4 = p4[c * 256 + i4] * gc;
        float v8 = p8[c * 64 + i8] * gc;
        mx = fmaxf(fmaxf(mx, xv), fmaxf(fmaxf(v2, v4), v8));
        sm += xv + v2 + v4 + v8;
    }
    comp[((size_t)b * 2) * 4096 + pix] = mx;
    comp[((size_t)b * 2 + 1) * 4096 + pix] = sm * (1.f / 1024.f);
}

// ---------------------------------------------------------------------------
// K4: 7x7 conv (2->1, pad 3, no bias) + BN(eval) + sigmoid -> spg[b][4096]
// ---------------------------------------------------------------------------
__global__ __launch_bounds__(256) void k4_spgate(
    const float* __restrict__ comp, const float* __restrict__ Wsp,
    const float* __restrict__ bn_g, const float* __restrict__ bn_b,
    const float* __restrict__ bn_m, const float* __restrict__ bn_v,
    float* __restrict__ spg)
{
    __shared__ float w[98];
    const int t = threadIdx.x;
    if (t < 98) w[t] = Wsp[t];
    __syncthreads();
    const int b = blockIdx.x >> 4;
    const int pix = ((blockIdx.x & 15) << 8) + t;
    const int h = pix >> 6, wx = pix & 63;
    const float* c0 = comp + (size_t)b * 2 * 4096;
    float acc = 0.f;
    for (int ci = 0; ci < 2; ci++)
        for (int kh = 0; kh < 7; kh++) {
            int hh = h + kh - 3;
            if (hh < 0 || hh >= 64) continue;
            for (int kw = 0; kw < 7; kw++) {
                int wwp = wx + kw - 3;
                if (wwp < 0 || wwp >= 64) continue;
                acc += c0[ci * 4096 + hh * 64 + wwp] * w[ci * 49 + kh * 7 + kw];
            }
        }
    float sc = rsqrtf(bn_v[0] + 1e-5f) * bn_g[0];
    float sp = (acc - bn_m[0]) * sc + bn_b[0];
    spg[b * 4096 + pix] = 1.f / (1.f + __expf(-sp));
}

// ---------------------------------------------------------------------------
// K6: projection GEMM.  out[b][o][n] = sum_c W[o][col_off+c]*src[b][c][n]
// o in [0,320): rows 0..31 Wq, 32..63 Wk, 64..319 Wv.
// add_up=1 (full-res pass): += bias + upsampled P2/P4/P8.
// Block: 256 thr, 64o x 64n tile, 4x4 per thread, K-chunks of 32.
// ---------------------------------------------------------------------------
__global__ __launch_bounds__(256) void k6_gemm(
    const float* __restrict__ Wq, const float* __restrict__ Wk, const float* __restrict__ Wv,
    int col_off, const float* __restrict__ src, int ns,
    float* __restrict__ outp, int add_up,
    const float* __restrict__ bq, const float* __restrict__ bk, const float* __restrict__ bv,
    const float* __restrict__ P2, const float* __restrict__ P4, const float* __restrict__ P8)
{
    __shared__ float At[32][68];
    __shared__ float Bt[32][64];
    const int b = blockIdx.z;
    const int o_base = blockIdx.y * 64;
    const int n_base = blockIdx.x * 64;
    const int t = threadIdx.x;
    const int tn = t >> 4, tm = t & 15;
    const int lk = t & 31, lo8 = t >> 5;
    const int ln = t & 63, lk4 = t >> 6;
    float acc[4][4];
    #pragma unroll
    for (int i = 0; i < 4; i++)
        #pragma unroll
        for (int j = 0; j < 4; j++) acc[i][j] = 0.f;
    for (int k0 = 0; k0 < 256; k0 += 32) {
        __syncthreads();
        #pragma unroll
        for (int r = 0; r < 8; r++) {
            int o = o_base + lo8 + 8 * r;
            const float* wrow = (o < 32) ? (Wq + (size_t)o * 1024)
                              : (o < 64) ? (Wk + (size_t)(o - 32) * 1024)
                                         : (Wv + (size_t)(o - 64) * 1024);
            At[lk][lo8 + 8 * r] = wrow[col_off + k0 + lk];
        }
        #pragma unroll
        for (int r = 0; r < 8; r++)
            Bt[lk4 + 4 * r][ln] = src[((size_t)b * 256 + k0 + lk4 + 4 * r) * ns + n_base + ln];
        __syncthreads();
        #pragma unroll
        for (int kk = 0; kk < 32; kk++) {
            float4 a = *(const float4*)&At[kk][4 * tn];
            float4 bb = *(const float4*)&Bt[kk][4 * tm];
            acc[0][0] += a.x * bb.x; acc[0][1] += a.x * bb.y; acc[0][2] += a.x * bb.z; acc[0][3] += a.x * bb.w;
            acc[1][0] += a.y * bb.x; acc[1][1] += a.y * bb.y; acc[1][2] += a.y * bb.z; acc[1][3] += a.y * bb.w;
            acc[2][0] += a.z * bb.x; acc[2][1] += a.z * bb.y; acc[2][2] += a.z * bb.z; acc[2][3] += a.z * bb.w;
            acc[3][0] += a.w * bb.x; acc[3][1] += a.w * bb.y; acc[3][2] += a.w * bb.z; acc[3][3] += a.w * bb.w;
        }
    }
    #pragma unroll
    for (int i = 0; i < 4; i++) {
        int o = o_base + 4 * tn + i;
        float bias = 0.f;
        if (add_up) bias = (o < 32) ? bq[o] : (o < 64) ? bk[o - 32] : bv[o - 64];
        #pragma unroll
        for (int j = 0; j < 4; j++) {
            int n = n_base + 4 * tm + j;
            float val = acc[i][j];
            if (add_up) {
                int h = n >> 6, w = n & 63;
                size_t ro = (size_t)b * 320 + o;
                val += bias + P2[ro * 1024 + ((h >> 1) << 5) + (w >> 1)]
                            + P4[ro * 256 + ((h >> 2) << 4) + (w >> 2)]
                            + P8[ro * 64 + ((h >> 3) << 3) + (w >> 3)];
            }
            outp[((size_t)b * 320 + o) * ns + n] = val;
        }
    }
}

// ---------------------------------------------------------------------------
// K7: flash-style attention. Block = (b, 64-query tile), 512 threads.
// Streams K/V in 32-wide m-chunks; online softmax; acc[256c x 64n] in regs
// (8c x 4n per thread). Epilogue: out = gamma*acc/l + x2.
// ---------------------------------------------------------------------------
__global__ __launch_bounds__(512) void k7_attn(
    const float* __restrict__ qkv, const float* __restrict__ x2,
    const float* __restrict__ gamma, float* __restrict__ outp)
{
    __shared__ float sq[32][64];
    __shared__ float sk[32][32];
    __shared__ float sv[256][33];   // pad -> stride 33: 2-way max on strided reads
    __shared__ float sp[64][33];
    __shared__ float red[16][64];
    __shared__ float smax[64], slsum[64], salpha[64];
    const int b = blockIdx.x >> 6;
    const int qbase = (blockIdx.x & 63) * 64;
    const int t = threadIdx.x;
    const float* qg = qkv + (size_t)b * 320 * 4096;
    const float* kg = qg + 32 * 4096;
    const float* vg = qg + 64 * 4096;
    #pragma unroll
    for (int r = 0; r < 4; r++) {
        int idx = t + 512 * r;
        sq[idx >> 6][idx & 63] = qg[(size_t)(idx >> 6) * 4096 + qbase + (idx & 63)];
    }
    if (t < 64) { smax[t] = -1e30f; slsum[t] = 0.f; }
    float acc[8][4];
    #pragma unroll
    for (int i = 0; i < 8; i++)
        #pragma unroll
        for (int j = 0; j < 4; j++) acc[i][j] = 0.f;
    const int n0e = (t >> 4) * 2, m0e = (t & 15) * 2;   // e-tile: 2n x 2m
    const int c0 = (t >> 4) * 8, n0a = (t & 15) * 4;    // acc-tile: 8c x 4n

    for (int mo = 0; mo < 4096; mo += 32) {
        __syncthreads();                                 // protect sk/sv/sp/salpha
        #pragma unroll
        for (int r = 0; r < 2; r++) {
            int idx = t + 512 * r;
            sk[idx >> 5][idx & 31] = kg[(size_t)(idx >> 5) * 4096 + mo + (idx & 31)];
        }
        #pragma unroll
        for (int r = 0; r < 4; r++) {
            int i4 = t + 512 * r;
            int c = i4 >> 3, m4 = (i4 & 7) * 4;
            float4 vv = ((const float4*)(vg + (size_t)c * 4096 + mo))[i4 & 7];
            sv[c][m4] = vv.x; sv[c][m4 + 1] = vv.y; sv[c][m4 + 2] = vv.z; sv[c][m4 + 3] = vv.w;
        }
        __syncthreads();
        float e00 = 0.f, e01 = 0.f, e10 = 0.f, e11 = 0.f;
        #pragma unroll
        for (int kk = 0; kk < 32; kk++) {
            float a0 = sq[kk][n0e], a1 = sq[kk][n0e + 1];
            float b0 = sk[kk][m0e], b1 = sk[kk][m0e + 1];
            e00 += a0 * b0; e01 += a0 * b1;
            e10 += a1 * b0; e11 += a1 * b1;
        }
        red[m0e >> 1][n0e] = fmaxf(e00, e01);
        red[m0e >> 1][n0e + 1] = fmaxf(e10, e11);
        __syncthreads();
        if (t < 64) {
            float cm = red[0][t];
            #pragma unroll
            for (int j = 1; j < 16; j++) cm = fmaxf(cm, red[j][t]);
            float m_old = smax[t];
            float m_new = fmaxf(m_old, cm);
            float al = __expf(m_old - m_new);
            smax[t] = m_new; salpha[t] = al; slsum[t] *= al;
        }
        __syncthreads();
        {
            float mr0 = smax[n0e], mr1 = smax[n0e + 1];
            float p00 = __expf(e00 - mr0), p01 = __expf(e01 - mr0);
            float p10 = __expf(e10 - mr1), p11 = __expf(e11 - mr1);
            sp[n0e][m0e] = p00; sp[n0e][m0e + 1] = p01;
            sp[n0e + 1][m0e] = p10; sp[n0e + 1][m0e + 1] = p11;
            red[m0e >> 1][n0e] = p00 + p01;
            red[m0e >> 1][n0e + 1] = p10 + p11;
        }
        __syncthreads();
        if (t < 64) {
            float s = 0.f;
            #pragma unroll
            for (int j = 0; j < 16; j++) s += red[j][t];
            slsum[t] += s;
        }
        {
            float al0 = salpha[n0a], al1 = salpha[n0a + 1];
            float al2 = salpha[n0a + 2], al3 = salpha[n0a + 3];
            #pragma unroll
            for (int i = 0; i < 8; i++) {
                acc[i][0] *= al0; acc[i][1] *= al1; acc[i][2] *= al2; acc[i][3] *= al3;
            }
            #pragma unroll 4
            for (int m = 0; m < 32; m++) {
                float pp0 = sp[n0a][m], pp1 = sp[n0a + 1][m];
                float pp2 = sp[n0a + 2][m], pp3 = sp[n0a + 3][m];
                #pragma unroll
                for (int i = 0; i < 8; i++) {
                    float vv = sv[c0 + i][m];
                    acc[i][0] += vv * pp0; acc[i][1] += vv * pp1;
                    acc[i][2] += vv * pp2; acc[i][3] += vv * pp3;
                }
            }
        }
    }
    __syncthreads();
    const float gm = gamma[0];
    #pragma unroll
    for (int j = 0; j < 4; j++) {
        float inv_l = 1.f / slsum[n0a + j];
        int n = qbase + n0a + j;
        #pragma unroll
        for (int i = 0; i < 8; i++) {
            size_t idx = ((size_t)b * 256 + c0 + i) * 4096 + n;
            outp[idx] = gm * acc[i][j] * inv_l + x2[idx];
        }
    }
}

// ---------------------------------------------------------------------------
extern "C" void kernel_launch(void* const* d_in, const int* in_sizes, int n_in,
                              void* d_out, int out_size, void* d_ws, size_t ws_size,
                              hipStream_t stream) {
    (void)in_sizes; (void)n_in; (void)out_size; (void)ws_size;
    const float* x    = (const float*)d_in[0];
    const float* W1   = (const float*)d_in[1];
    const float* b1   = (const float*)d_in[2];
    const float* W2   = (const float*)d_in[3];
    const float* b2   = (const float*)d_in[4];
    const float* Wq   = (const float*)d_in[5];
    const float* bq   = (const float*)d_in[6];
    const float* Wk   = (const float*)d_in[7];
    const float* bk   = (const float*)d_in[8];
    const float* Wv   = (const float*)d_in[9];
    const float* bv   = (const float*)d_in[10];
    const float* gam  = (const float*)d_in[11];
    const float* Wsp  = (const float*)d_in[12];
    const float* bn_g = (const float*)d_in[13];
    const float* bn_b = (const float*)d_in[14];
    const float* bn_m = (const float*)d_in[15];
    const float* bn_v = (const float*)d_in[16];

    float* ws = (float*)d_ws;
    float* bm2   = ws; ws += (size_t)4 * 256 * 1024;
    float* bm4   = ws; ws += (size_t)4 * 256 * 256;
    float* bm8   = ws; ws += (size_t)4 * 256 * 64;
    float* featA = ws; ws += 1024;
    float* fm1   = ws; ws += 1024;
    float* fm2   = ws; ws += 1024;
    float* fm4   = ws; ws += 1024;
    float* fm8   = ws; ws += 1024;
    float* g     = ws; ws += 1024;
    float* comp  = ws; ws += (size_t)4 * 2 * 4096;
    float* spg   = ws; ws += (size_t)4 * 4096;
    float* x2    = ws; ws += (size_t)4 * 256 * 4096;
    float* bm2b  = ws; ws += (size_t)4 * 256 * 1024;
    float* bm4b  = ws; ws += (size_t)4 * 256 * 256;
    float* bm8b  = ws; ws += (size_t)4 * 256 * 64;
    float* P2    = ws; ws += (size_t)4 * 320 * 1024;
    float* P4    = ws; ws += (size_t)4 * 320 * 256;
    float* P8    = ws; ws += (size_t)4 * 320 * 64;
    float* qkv   = ws; ws += (size_t)4 * 320 * 4096;

    // Stage 1: channel gate
    k_pyramid<<<1024, 256, 0, stream>>>(x, nullptr, nullptr, nullptr,
                                        bm2, bm4, bm8, featA, fm1, fm2, fm4, fm8, 0);
    k2_gate<<<4, 256, 0, stream>>>(featA, fm1, fm2, fm4, fm8, W1, b1, W2, b2, g);
    // Stage 2: spatial gate
    k3_comp<<<64, 256, 0, stream>>>(x, bm2, bm4, bm8, g, comp);
    k4_spgate<<<64, 256, 0, stream>>>(comp, Wsp, bn_g, bn_b, bn_m, bn_v, spg);
    // x2 = x*g*spg, + its pyramid
    k_pyramid<<<1024, 256, 0, stream>>>(x, g, spg, x2,
                                        bm2b, bm4b, bm8b,
                                        nullptr, nullptr, nullptr, nullptr, nullptr, 1);
    // Stage 3: q/k/v projections, multiscale-decomposed
    k6_gemm<<<dim3(16, 5, 4), 256, 0, stream>>>(Wq, Wk, Wv, 0,   bm2b, 1024, P2, 0,
                                                nullptr, nullptr, nullptr, nullptr, nullptr, nullptr);
    k6_gemm<<<dim3(4, 5, 4), 256, 0, stream>>>(Wq, Wk, Wv, 256, bm4b, 256,  P4, 0,
                                                nullptr, nullptr, nullptr, nullptr, nullptr, nullptr);
    k6_gemm<<<dim3(1, 5, 4), 256, 0, stream>>>(Wq, Wk, Wv, 512, bm8b, 64,   P8, 0,
                                                nullptr, nullptr, nullptr, nullptr, nullptr, nullptr);
    k6_gemm<<<dim3(64, 5, 4), 256, 0, stream>>>(Wq, Wk, Wv, 768, x2, 4096, qkv, 1,
                                                bq, bk, bv, P2, P4, P8);
    // Flash attention + residual
    k7_attn<<<256, 512, 0, stream>>>(qkv, x2, gam, (float*)d_out);
}

// Round 2
// 360.952 us; speedup vs baseline: 3.3474x; 3.3474x over previous
//
#include <hip/hip_runtime.h>
#include <math.h>

// Shapes (fixed): B=4, C=256, H=W=64, N=4096, 4C=1024, c8=32, r=16.

typedef float f32x4 __attribute__((ext_vector_type(4)));
typedef short s16x8 __attribute__((ext_vector_type(8)));
union FRAG { uint4 u; s16x8 s; };

__device__ __forceinline__ unsigned short f2bf(float f) {
    union { float f; unsigned int u; } v; v.f = f;
    unsigned int r = v.u + 0x7FFFu + ((v.u >> 16) & 1u);
    return (unsigned short)(r >> 16);
}

// ---------------------------------------------------------------------------
// K1/K5: per-(b,c) plane -> block-mean pyramid (+ feats in mode 0, x2 in mode 1)
// ---------------------------------------------------------------------------
__global__ __launch_bounds__(256) void k_pyramid(
    const float* __restrict__ xin, const float* __restrict__ gch,
    const float* __restrict__ spg, float* __restrict__ x2out,
    float* __restrict__ bm2, float* __restrict__ bm4, float* __restrict__ bm8,
    float* __restrict__ featA, float* __restrict__ fm1, float* __restrict__ fm2,
    float* __restrict__ fm4, float* __restrict__ fm8, int mode)
{
    __shared__ float sx[4096];
    __shared__ float s2[1024];
    __shared__ float s4[256];
    __shared__ float red[256];
    const int bc = blockIdx.x;
    const int b = bc >> 8;
    const int t = threadIdx.x;
    const float* xp = xin + (size_t)bc * 4096;
    float gc = 1.f;
    if (mode == 1) gc = gch[bc];
    float sum = 0.f, mx = -1e30f;
    for (int r = 0; r < 4; r++) {
        int i4 = t + 256 * r;
        float4 v = ((const float4*)xp)[i4];
        if (mode == 1) {
            float4 sg = ((const float4*)(spg + (size_t)b * 4096))[i4];
            v.x *= gc * sg.x; v.y *= gc * sg.y; v.z *= gc * sg.z; v.w *= gc * sg.w;
            ((float4*)(x2out + (size_t)bc * 4096))[i4] = v;
        } else {
            sum += v.x + v.y + v.z + v.w;
            mx = fmaxf(mx, fmaxf(fmaxf(v.x, v.y), fmaxf(v.z, v.w)));
        }
        ((float4*)sx)[i4] = v;
    }
    __syncthreads();
    float mx2 = -1e30f;
    for (int r = 0; r < 4; r++) {
        int i = t + 256 * r;
        int r2 = i >> 5, c2 = i & 31;
        int p0 = 128 * r2 + 2 * c2;
        float v = 0.25f * (sx[p0] + sx[p0 + 1] + sx[p0 + 64] + sx[p0 + 65]);
        s2[i] = v;
        bm2[(size_t)bc * 1024 + i] = v;
        mx2 = fmaxf(mx2, v);
    }
    __syncthreads();
    float mx4;
    {
        int r4 = t >> 4, c4 = t & 15;
        int p0 = 64 * r4 + 2 * c4;
        float v = 0.25f * (s2[p0] + s2[p0 + 1] + s2[p0 + 32] + s2[p0 + 33]);
        s4[t] = v;
        bm4[(size_t)bc * 256 + t] = v;
        mx4 = v;
    }
    __syncthreads();
    float mx8 = -1e30f;
    if (t < 64) {
        int r8 = t >> 3, c8 = t & 7;
        int p0 = 32 * r8 + 2 * c8;
        float v = 0.25f * (s4[p0] + s4[p0 + 1] + s4[p0 + 16] + s4[p0 + 17]);
        bm8[(size_t)bc * 64 + t] = v;
        mx8 = v;
    }
    if (mode == 0) {
        red[t] = sum; __syncthreads();
        for (int s = 128; s > 0; s >>= 1) { if (t < s) red[t] += red[t + s]; __syncthreads(); }
        if (t == 0) featA[bc] = red[0] * (1.f / 4096.f);
        __syncthreads();
        red[t] = mx; __syncthreads();
        for (int s = 128; s > 0; s >>= 1) { if (t < s) red[t] = fmaxf(red[t], red[t + s]); __syncthreads(); }
        if (t == 0) fm1[bc] = red[0];
        __syncthreads();
        red[t] = mx2; __syncthreads();
        for (int s = 128; s > 0; s >>= 1) { if (t < s) red[t] = fmaxf(red[t], red[t + s]); __syncthreads(); }
        if (t == 0) fm2[bc] = red[0];
        __syncthreads();
        red[t] = mx4; __syncthreads();
        for (int s = 128; s > 0; s >>= 1) { if (t < s) red[t] = fmaxf(red[t], red[t + s]); __syncthreads(); }
        if (t == 0) fm4[bc] = red[0];
        __syncthreads();
        red[t] = mx8; __syncthreads();
        for (int s = 128; s > 0; s >>= 1) { if (t < s) red[t] = fmaxf(red[t], red[t + s]); __syncthreads(); }
        if (t == 0) fm8[bc] = red[0];
    }
}

// ---------------------------------------------------------------------------
// K2: channel-gate MLP
// ---------------------------------------------------------------------------
__global__ __launch_bounds__(256) void k2_gate(
    const float* __restrict__ featA, const float* __restrict__ fm1,
    const float* __restrict__ fm2, const float* __restrict__ fm4, const float* __restrict__ fm8,
    const float* __restrict__ W1, const float* __restrict__ b1,
    const float* __restrict__ W2, const float* __restrict__ b2,
    float* __restrict__ g)
{
    __shared__ float sf[5][256];
    __shared__ float sh[5][16];
    __shared__ float hs[16];
    const int b = blockIdx.x, t = threadIdx.x;
    sf[0][t] = featA[b * 256 + t];
    sf[1][t] = fm1[b * 256 + t];
    sf[2][t] = fm2[b * 256 + t];
    sf[3][t] = fm4[b * 256 + t];
    sf[4][t] = fm8[b * 256 + t];
    __syncthreads();
    if (t < 80) {
        int f = t / 16, j = t % 16;
        float a = b1[j];
        for (int c = 0; c < 256; c++) a += sf[f][c] * W1[c * 16 + j];
        sh[f][j] = fmaxf(a, 0.f);
    }
    __syncthreads();
    if (t < 16) hs[t] = 4.f * sh[0][t] + sh[1][t] + sh[2][t] + sh[3][t] + sh[4][t];
    __syncthreads();
    float a = 8.f * b2[t];
    for (int j = 0; j < 16; j++) a += hs[j] * W2[j * 256 + t];
    g[b * 256 + t] = 1.f / (1.f + __expf(-a));
}

// ---------------------------------------------------------------------------
// K3: spatial-gate input (max & mean over 4C multiscale channels of g*x)
// ---------------------------------------------------------------------------
__global__ __launch_bounds__(256) void k3_comp(
    const float* __restrict__ x, const float* __restrict__ bm2,
    const float* __restrict__ bm4, const float* __restrict__ bm8,
    const float* __restrict__ g, float* __restrict__ comp)
{
    __shared__ float sg[256];
    const int b = blockIdx.x >> 4;
    const int pix = ((blockIdx.x & 15) << 8) + threadIdx.x;
    sg[threadIdx.x] = g[(b << 8) + threadIdx.x];
    __syncthreads();
    const int h = pix >> 6, w = pix & 63;
    const int i2 = ((h >> 1) << 5) + (w >> 1);
    const int i4 = ((h >> 2) << 4) + (w >> 2);
    const int i8 = ((h >> 3) << 3) + (w >> 3);
    const float* xb = x + ((size_t)b << 8) * 4096;
    const float* p2 = bm2 + ((size_t)b << 8) * 1024;
    const float* p4 = bm4 + ((size_t)b << 8) * 256;
    const float* p8 = bm8 + ((size_t)b << 8) * 64;
    float mx = -1e30f, sm = 0.f;
    for (int c = 0; c < 256; c++) {
        float gc = sg[c];
        float xv = xb[(size_t)c * 4096 + pix] * gc;
        float v2 = p2[c * 1024 + i2] * gc;
        float v4 = p4[c * 256 + i4] * gc;
        float v8 = p8[c * 64 + i8] * gc;
        mx = fmaxf(fmaxf(mx, xv), fmaxf(fmaxf(v2, v4), v8));
        sm += xv + v2 + v4 + v8;
    }
    comp[((size_t)b * 2) * 4096 + pix] = mx;
    comp[((size_t)b * 2 + 1) * 4096 + pix] = sm * (1.f / 1024.f);
}

// ---------------------------------------------------------------------------
// K4: 7x7 conv (2->1, pad 3, no bias) + BN(eval) + sigmoid -> spg
// ---------------------------------------------------------------------------
__global__ __launch_bounds__(256) void k4_spgate(
    const float* __restrict__ comp, const float* __restrict__ Wsp,
    const float* __restrict__ bn_g, const float* __restrict__ bn_b,
    const float* __restrict__ bn_m, const float* __restrict__ bn_v,
    float* __restrict__ spg)
{
    __shared__ float w[98];
    const int t = threadIdx.x;
    if (t < 98) w[t] = Wsp[t];
    __syncthreads();
    const int b = blockIdx.x >> 4;
    const int pix = ((blockIdx.x & 15) << 8) + t;
    const int h = pix >> 6, wx = pix & 63;
    const float* c0 = comp + (size_t)b * 2 * 4096;
    float acc = 0.f;
    for (int ci = 0; ci < 2; ci++)
        for (int kh = 0; kh < 7; kh++) {
            int hh = h + kh - 3;
            if (hh < 0 || hh >= 64) continue;
            for (int kw = 0; kw < 7; kw++) {
                int wwp = wx + kw - 3;
                if (wwp < 0 || wwp >= 64) continue;
                acc += c0[ci * 4096 + hh * 64 + wwp] * w[ci * 49 + kh * 7 + kw];
            }
        }
    float sc = rsqrtf(bn_v[0] + 1e-5f) * bn_g[0];
    float sp = (acc - bn_m[0]) * sc + bn_b[0];
    spg[b * 4096 + pix] = 1.f / (1.f + __expf(-sp));
}

// ---------------------------------------------------------------------------
// K6: projection GEMM.  o in [0,320): 0..31 Wq, 32..63 Wk, 64..319 Wv.
// add_up=0: write fp32 tile outp[b][320][ns]   (low-res P2/P4/P8 passes)
// add_up=1: += bias + upsampled P2/P4/P8; q/k rows -> fp32 qk[b][64][4096],
//           v rows -> bf16 vB[b][256][4096]
// ---------------------------------------------------------------------------
__global__ __launch_bounds__(256) void k6_gemm(
    const float* __restrict__ Wq, const float* __restrict__ Wk, const float* __restrict__ Wv,
    int col_off, const float* __restrict__ src, int ns,
    float* __restrict__ outp, int add_up,
    const float* __restrict__ bq, const float* __restrict__ bk, const float* __restrict__ bv,
    const float* __restrict__ P2, const float* __restrict__ P4, const float* __restrict__ P8,
    float* __restrict__ qk, unsigned short* __restrict__ vB)
{
    __shared__ float At[32][68];
    __shared__ float Bt[32][64];
    const int b = blockIdx.z;
    const int o_base = blockIdx.y * 64;
    const int n_base = blockIdx.x * 64;
    const int t = threadIdx.x;
    const int tn = t >> 4, tm = t & 15;
    const int lk = t & 31, lo8 = t >> 5;
    const int ln = t & 63, lk4 = t >> 6;
    float acc[4][4];
    #pragma unroll
    for (int i = 0; i < 4; i++)
        #pragma unroll
        for (int j = 0; j < 4; j++) acc[i][j] = 0.f;
    for (int k0 = 0; k0 < 256; k0 += 32) {
        __syncthreads();
        #pragma unroll
        for (int r = 0; r < 8; r++) {
            int o = o_base + lo8 + 8 * r;
            const float* wrow = (o < 32) ? (Wq + (size_t)o * 1024)
                              : (o < 64) ? (Wk + (size_t)(o - 32) * 1024)
                                         : (Wv + (size_t)(o - 64) * 1024);
            At[lk][lo8 + 8 * r] = wrow[col_off + k0 + lk];
        }
        #pragma unroll
        for (int r = 0; r < 8; r++)
            Bt[lk4 + 4 * r][ln] = src[((size_t)b * 256 + k0 + lk4 + 4 * r) * ns + n_base + ln];
        __syncthreads();
        #pragma unroll
        for (int kk = 0; kk < 32; kk++) {
            float4 a = *(const float4*)&At[kk][4 * tn];
            float4 bb = *(const float4*)&Bt[kk][4 * tm];
            acc[0][0] += a.x * bb.x; acc[0][1] += a.x * bb.y; acc[0][2] += a.x * bb.z; acc[0][3] += a.x * bb.w;
            acc[1][0] += a.y * bb.x; acc[1][1] += a.y * bb.y; acc[1][2] += a.y * bb.z; acc[1][3] += a.y * bb.w;
            acc[2][0] += a.z * bb.x; acc[2][1] += a.z * bb.y; acc[2][2] += a.z * bb.z; acc[2][3] += a.z * bb.w;
            acc[3][0] += a.w * bb.x; acc[3][1] += a.w * bb.y; acc[3][2] += a.w * bb.z; acc[3][3] += a.w * bb.w;
        }
    }
    #pragma unroll
    for (int i = 0; i < 4; i++) {
        int o = o_base + 4 * tn + i;
        if (add_up) {
            float bias = (o < 32) ? bq[o] : (o < 64) ? bk[o - 32] : bv[o - 64];
            size_t ro = (size_t)b * 320 + o;
            float vals[4];
            #pragma unroll
            for (int j = 0; j < 4; j++) {
                int n = n_base + 4 * tm + j;
                int h = n >> 6, w = n & 63;
                vals[j] = acc[i][j] + bias
                        + P2[ro * 1024 + ((h >> 1) << 5) + (w >> 1)]
                        + P4[ro * 256 + ((h >> 2) << 4) + (w >> 2)]
                        + P8[ro * 64 + ((h >> 3) << 3) + (w >> 3)];
            }
            if (o < 64) {
                #pragma unroll
                for (int j = 0; j < 4; j++)
                    qk[((size_t)b * 64 + o) * 4096 + n_base + 4 * tm + j] = vals[j];
            } else {
                uint2 pk;
                pk.x = (unsigned int)f2bf(vals[0]) | ((unsigned int)f2bf(vals[1]) << 16);
                pk.y = (unsigned int)f2bf(vals[2]) | ((unsigned int)f2bf(vals[3]) << 16);
                *(uint2*)(vB + ((size_t)b * 256 + (o - 64)) * 4096 + n_base + 4 * tm) = pk;
            }
        } else {
            #pragma unroll
            for (int j = 0; j < 4; j++)
                outp[((size_t)b * 320 + o) * ns + n_base + 4 * tm + j] = acc[i][j];
        }
    }
}

// ---------------------------------------------------------------------------
// K6T: qk fp32 [b][64][4096] -> qT/kT bf16 [b][4096][32]  (MFMA frag layouts)
// Reads coalesced per-c; writes 64B/thread contiguous.
// ---------------------------------------------------------------------------
__global__ __launch_bounds__(256) void k6t(
    const float* __restrict__ qk, unsigned short* __restrict__ qT,
    unsigned short* __restrict__ kT)
{
    const int b = blockIdx.x >> 4;
    const int n = ((blockIdx.x & 15) << 8) + threadIdx.x;
    unsigned int q[16], kk[16];
    #pragma unroll
    for (int c = 0; c < 32; c += 2) {
        float q0 = qk[((size_t)b * 64 + c) * 4096 + n];
        float q1 = qk[((size_t)b * 64 + c + 1) * 4096 + n];
        q[c >> 1] = (unsigned int)f2bf(q0) | ((unsigned int)f2bf(q1) << 16);
        float k0 = qk[((size_t)b * 64 + 32 + c) * 4096 + n];
        float k1 = qk[((size_t)b * 64 + 33 + c) * 4096 + n];
        kk[c >> 1] = (unsigned int)f2bf(k0) | ((unsigned int)f2bf(k1) << 16);
    }
    uint4* qo = (uint4*)(qT + ((size_t)b * 4096 + n) * 32);
    uint4* ko = (uint4*)(kT + ((size_t)b * 4096 + n) * 32);
    #pragma unroll
    for (int r = 0; r < 4; r++) {
        uint4 a; a.x = q[4 * r]; a.y = q[4 * r + 1]; a.z = q[4 * r + 2]; a.w = q[4 * r + 3];
        qo[r] = a;
        uint4 bb; bb.x = kk[4 * r]; bb.y = kk[4 * r + 1]; bb.z = kk[4 * r + 2]; bb.w = kk[4 * r + 3];
        ko[r] = bb;
    }
}

// ---------------------------------------------------------------------------
// K7: MFMA flash attention. Block = (b, 64-query tile), 256 thr / 4 waves.
// Wave w: computes E^T n-tile w via mfma(K^T[m][c], Q^T[c][n]) (one MFMA per
// 16x16 tile, K=32 = channel count); owns O c-stripe [64w,64w+64).
// Online softmax per lane-column (C-layout col = n); P round-trips through
// 8.7KB LDS to B-frag layout; V A-frags straight from global bf16.
// ---------------------------------------------------------------------------
__global__ __launch_bounds__(256) void k7_attn(
    const unsigned short* __restrict__ qT, const unsigned short* __restrict__ kT,
    const unsigned short* __restrict__ vB, const float* __restrict__ x2,
    const float* __restrict__ gamma, float* __restrict__ outp)
{
    __shared__ unsigned short PL[64][72];   // [n][m], pad 72 (144B rows, 16B-mult)
    __shared__ float salpha[64];
    __shared__ float slsum[64];
    const int b = blockIdx.x >> 6;
    const int qbase = (blockIdx.x & 63) << 6;
    const int t = threadIdx.x;
    const int w_ = t >> 6, lane = t & 63;
    const int quad = lane >> 4, l16 = lane & 15;

    // resident Q B-frag: B[k=c=quad*8+j][n=l16] from qT[b][qbase+16w+l16][quad*8..]
    FRAG qf;
    qf.u = *(const uint4*)(qT + ((size_t)(b * 4096 + qbase + 16 * w_ + l16)) * 32 + quad * 8);

    f32x4 acc[4][4];
    #pragma unroll
    for (int ct = 0; ct < 4; ct++)
        #pragma unroll
        for (int nt = 0; nt < 4; nt++) { acc[ct][nt][0] = 0.f; acc[ct][nt][1] = 0.f; acc[ct][nt][2] = 0.f; acc[ct][nt][3] = 0.f; }
    float m_run = -1e30f, l_run = 0.f;
    const unsigned short* kTb = kT + (size_t)b * 4096 * 32;
    const unsigned short* vBb = vB + (size_t)b * 256 * 4096;

    for (int mo = 0; mo < 4096; mo += 64) {
        // --- QK^T: E^T[m][n], 4 m-tiles for this wave's n-tile ---
        f32x4 e[4];
        #pragma unroll
        for (int mt = 0; mt < 4; mt++) {
            FRAG kf;
            kf.u = *(const uint4*)(kTb + (size_t)(mo + 16 * mt + l16) * 32 + quad * 8);
            f32x4 z; z[0] = 0.f; z[1] = 0.f; z[2] = 0.f; z[3] = 0.f;
            e[mt] = __builtin_amdgcn_mfma_f32_16x16x32_bf16(kf.s, qf.s, z, 0, 0, 0);
        }
        // --- online softmax: col n = 16w+l16; rows m spread over quads/regs ---
        float pmax = e[0][0];
        #pragma unroll
        for (int mt = 0; mt < 4; mt++)
            #pragma unroll
            for (int r = 0; r < 4; r++) pmax = fmaxf(pmax, e[mt][r]);
        pmax = fmaxf(pmax, __shfl_xor(pmax, 16));
        pmax = fmaxf(pmax, __shfl_xor(pmax, 32));
        float mnew = fmaxf(m_run, pmax);
        float alpha = __expf(m_run - mnew);
        m_run = mnew;
        float ps = 0.f;
        uint2 pk[4];
        #pragma unroll
        for (int mt = 0; mt < 4; mt++) {
            union { float f; unsigned int u; } p0, p1, p2, p3;
            p0.f = __expf(e[mt][0] - mnew);
            p1.f = __expf(e[mt][1] - mnew);
            p2.f = __expf(e[mt][2] - mnew);
            p3.f = __expf(e[mt][3] - mnew);
            ps += p0.f + p1.f + p2.f + p3.f;
            pk[mt].x = __builtin_amdgcn_perm(p1.u, p0.u, 0x07060302u);  // trunc-bf16 pair
            pk[mt].y = __builtin_amdgcn_perm(p3.u, p2.u, 0x07060302u);
        }
        l_run = l_run * alpha + ps;
        __syncthreads();   // previous chunk's PV reads of PL/salpha done
        #pragma unroll
        for (int mt = 0; mt < 4; mt++)
            *(uint2*)&PL[16 * w_ + l16][16 * mt + 4 * quad] = pk[mt];
        if (quad == 0) salpha[16 * w_ + l16] = alpha;
        __syncthreads();   // PL/salpha visible
        // --- rescale O by alpha(n) ---
        float al[4];
        #pragma unroll
        for (int nt = 0; nt < 4; nt++) al[nt] = salpha[16 * nt + l16];
        #pragma unroll
        for (int ct = 0; ct < 4; ct++)
            #pragma unroll
            for (int nt = 0; nt < 4; nt++) acc[ct][nt] *= al[nt];
        // --- PV: O[c][n] += V[c][m] * P^T[m][n] ---
        #pragma unroll
        for (int kh = 0; kh < 2; kh++) {
            FRAG av[4], bp[4];
            #pragma unroll
            for (int ct = 0; ct < 4; ct++)
                av[ct].u = *(const uint4*)(vBb + (size_t)(64 * w_ + 16 * ct + l16) * 4096
                                           + mo + 32 * kh + quad * 8);
            #pragma unroll
            for (int nt = 0; nt < 4; nt++)
                bp[nt].u = *(const uint4*)&PL[16 * nt + l16][32 * kh + quad * 8];
            #pragma unroll
            for (int ct = 0; ct < 4; ct++)
                #pragma unroll
                for (int nt = 0; nt < 4; nt++)
                    acc[ct][nt] = __builtin_amdgcn_mfma_f32_16x16x32_bf16(av[ct].s, bp[nt].s, acc[ct][nt], 0, 0, 0);
        }
    }
    // --- epilogue: reduce l across quads, share 1/l, write out ---
    float lt = l_run + __shfl_xor(l_run, 16);
    lt += __shfl_xor(lt, 32);
    if (quad == 0) slsum[16 * w_ + l16] = lt;
    __syncthreads();
    const float gm = gamma[0];
    float invl[4];
    #pragma unroll
    for (int nt = 0; nt < 4; nt++) invl[nt] = 1.f / slsum[16 * nt + l16];
    #pragma unroll
    for (int ct = 0; ct < 4; ct++) {
        #pragma unroll
        for (int nt = 0; nt < 4; nt++) {
            #pragma unroll
            for (int r = 0; r < 4; r++) {
                int c = 64 * w_ + 16 * ct + 4 * quad + r;
                int n = qbase + 16 * nt + l16;
                size_t idx = ((size_t)b * 256 + c) * 4096 + n;
                outp[idx] = gm * acc[ct][nt][r] * invl[nt] + x2[idx];
            }
        }
    }
}

// ---------------------------------------------------------------------------
extern "C" void kernel_launch(void* const* d_in, const int* in_sizes, int n_in,
                              void* d_out, int out_size, void* d_ws, size_t ws_size,
                              hipStream_t stream) {
    (void)in_sizes; (void)n_in; (void)out_size; (void)ws_size;
    const float* x    = (const float*)d_in[0];
    const float* W1   = (const float*)d_in[1];
    const float* b1   = (const float*)d_in[2];
    const float* W2   = (const float*)d_in[3];
    const float* b2   = (const float*)d_in[4];
    const float* Wq   = (const float*)d_in[5];
    const float* bq   = (const float*)d_in[6];
    const float* Wk   = (const float*)d_in[7];
    const float* bk   = (const float*)d_in[8];
    const float* Wv   = (const float*)d_in[9];
    const float* bv   = (const float*)d_in[10];
    const float* gam  = (const float*)d_in[11];
    const float* Wsp  = (const float*)d_in[12];
    const float* bn_g = (const float*)d_in[13];
    const float* bn_b = (const float*)d_in[14];
    const float* bn_m = (const float*)d_in[15];
    const float* bn_v = (const float*)d_in[16];

    float* ws = (float*)d_ws;
    float* bm2   = ws; ws += (size_t)4 * 256 * 1024;
    float* bm4   = ws; ws += (size_t)4 * 256 * 256;
    float* bm8   = ws; ws += (size_t)4 * 256 * 64;
    float* featA = ws; ws += 1024;
    float* fm1   = ws; ws += 1024;
    float* fm2   = ws; ws += 1024;
    float* fm4   = ws; ws += 1024;
    float* fm8   = ws; ws += 1024;
    float* g     = ws; ws += 1024;
    float* comp  = ws; ws += (size_t)4 * 2 * 4096;
    float* spg   = ws; ws += (size_t)4 * 4096;
    float* x2    = ws; ws += (size_t)4 * 256 * 4096;
    float* bm2b  = ws; ws += (size_t)4 * 256 * 1024;
    float* bm4b  = ws; ws += (size_t)4 * 256 * 256;
    float* bm8b  = ws; ws += (size_t)4 * 256 * 64;
    float* P2    = ws; ws += (size_t)4 * 320 * 1024;
    float* P4    = ws; ws += (size_t)4 * 320 * 256;
    float* P8    = ws; ws += (size_t)4 * 320 * 64;
    float* qkf   = ws; ws += (size_t)4 * 64 * 4096;           // fp32 q|k rows
    unsigned short* qT = (unsigned short*)ws; ws += (size_t)4 * 4096 * 32 / 2;
    unsigned short* kT = (unsigned short*)ws; ws += (size_t)4 * 4096 * 32 / 2;
    unsigned short* vB = (unsigned short*)ws; ws += (size_t)4 * 256 * 4096 / 2;

    // Stage 1: channel gate
    k_pyramid<<<1024, 256, 0, stream>>>(x, nullptr, nullptr, nullptr,
                                        bm2, bm4, bm8, featA, fm1, fm2, fm4, fm8, 0);
    k2_gate<<<4, 256, 0, stream>>>(featA, fm1, fm2, fm4, fm8, W1, b1, W2, b2, g);
    // Stage 2: spatial gate
    k3_comp<<<64, 256, 0, stream>>>(x, bm2, bm4, bm8, g, comp);
    k4_spgate<<<64, 256, 0, stream>>>(comp, Wsp, bn_g, bn_b, bn_m, bn_v, spg);
    k_pyramid<<<1024, 256, 0, stream>>>(x, g, spg, x2,
                                        bm2b, bm4b, bm8b,
                                        nullptr, nullptr, nullptr, nullptr, nullptr, 1);
    // Stage 3: q/k/v projections, multiscale-decomposed
    k6_gemm<<<dim3(16, 5, 4), 256, 0, stream>>>(Wq, Wk, Wv, 0,   bm2b, 1024, P2, 0,
                                                nullptr, nullptr, nullptr, nullptr, nullptr, nullptr,
                                                nullptr, nullptr);
    k6_gemm<<<dim3(4, 5, 4), 256, 0, stream>>>(Wq, Wk, Wv, 256, bm4b, 256,  P4, 0,
                                                nullptr, nullptr, nullptr, nullptr, nullptr, nullptr,
                                                nullptr, nullptr);
    k6_gemm<<<dim3(1, 5, 4), 256, 0, stream>>>(Wq, Wk, Wv, 512, bm8b, 64,   P8, 0,
                                                nullptr, nullptr, nullptr, nullptr, nullptr, nullptr,
                                                nullptr, nullptr);
    k6_gemm<<<dim3(64, 5, 4), 256, 0, stream>>>(Wq, Wk, Wv, 768, x2, 4096, nullptr, 1,
                                                bq, bk, bv, P2, P4, P8, qkf, vB);
    k6t<<<64, 256, 0, stream>>>(qkf, qT, kT);
    // MFMA flash attention + residual
    k7_attn<<<256, 256, 0, stream>>>(qT, kT, vB, x2, gam, (float*)d_out);
}

// Round 4
// 334.036 us; speedup vs baseline: 3.6171x; 1.0806x over previous
//
#include <hip/hip_runtime.h>
#include <math.h>

// Shapes (fixed): B=4, C=256, H=W=64, N=4096, 4C=1024, c8=32, r=16.

typedef float f32x4 __attribute__((ext_vector_type(4)));
typedef short s16x8 __attribute__((ext_vector_type(8)));
union FRAG { uint4 u; s16x8 s; };

__device__ __forceinline__ unsigned short f2bf(float f) {
    union { float f; unsigned int u; } v; v.f = f;
    unsigned int r = v.u + 0x7FFFu + ((v.u >> 16) & 1u);
    return (unsigned short)(r >> 16);
}

// ---------------------------------------------------------------------------
// K1/K5: per-(b,c) plane -> block-mean pyramid (+ feats in mode 0, x2 in mode 1)
// ---------------------------------------------------------------------------
__global__ __launch_bounds__(256) void k_pyramid(
    const float* __restrict__ xin, const float* __restrict__ gch,
    const float* __restrict__ spg, float* __restrict__ x2out,
    float* __restrict__ bm2, float* __restrict__ bm4, float* __restrict__ bm8,
    float* __restrict__ featA, float* __restrict__ fm1, float* __restrict__ fm2,
    float* __restrict__ fm4, float* __restrict__ fm8, int mode)
{
    __shared__ float sx[4096];
    __shared__ float s2[1024];
    __shared__ float s4[256];
    __shared__ float red[256];
    const int bc = blockIdx.x;
    const int b = bc >> 8;
    const int t = threadIdx.x;
    const float* xp = xin + (size_t)bc * 4096;
    float gc = 1.f;
    if (mode == 1) gc = gch[bc];
    float sum = 0.f, mx = -1e30f;
    for (int r = 0; r < 4; r++) {
        int i4 = t + 256 * r;
        float4 v = ((const float4*)xp)[i4];
        if (mode == 1) {
            float4 sg = ((const float4*)(spg + (size_t)b * 4096))[i4];
            v.x *= gc * sg.x; v.y *= gc * sg.y; v.z *= gc * sg.z; v.w *= gc * sg.w;
            ((float4*)(x2out + (size_t)bc * 4096))[i4] = v;
        } else {
            sum += v.x + v.y + v.z + v.w;
            mx = fmaxf(mx, fmaxf(fmaxf(v.x, v.y), fmaxf(v.z, v.w)));
        }
        ((float4*)sx)[i4] = v;
    }
    __syncthreads();
    float mx2 = -1e30f;
    for (int r = 0; r < 4; r++) {
        int i = t + 256 * r;
        int r2 = i >> 5, c2 = i & 31;
        int p0 = 128 * r2 + 2 * c2;
        float v = 0.25f * (sx[p0] + sx[p0 + 1] + sx[p0 + 64] + sx[p0 + 65]);
        s2[i] = v;
        bm2[(size_t)bc * 1024 + i] = v;
        mx2 = fmaxf(mx2, v);
    }
    __syncthreads();
    float mx4;
    {
        int r4 = t >> 4, c4 = t & 15;
        int p0 = 64 * r4 + 2 * c4;
        float v = 0.25f * (s2[p0] + s2[p0 + 1] + s2[p0 + 32] + s2[p0 + 33]);
        s4[t] = v;
        bm4[(size_t)bc * 256 + t] = v;
        mx4 = v;
    }
    __syncthreads();
    float mx8 = -1e30f;
    if (t < 64) {
        int r8 = t >> 3, c8 = t & 7;
        int p0 = 32 * r8 + 2 * c8;
        float v = 0.25f * (s4[p0] + s4[p0 + 1] + s4[p0 + 16] + s4[p0 + 17]);
        bm8[(size_t)bc * 64 + t] = v;
        mx8 = v;
    }
    if (mode == 0) {
        red[t] = sum; __syncthreads();
        for (int s = 128; s > 0; s >>= 1) { if (t < s) red[t] += red[t + s]; __syncthreads(); }
        if (t == 0) featA[bc] = red[0] * (1.f / 4096.f);
        __syncthreads();
        red[t] = mx; __syncthreads();
        for (int s = 128; s > 0; s >>= 1) { if (t < s) red[t] = fmaxf(red[t], red[t + s]); __syncthreads(); }
        if (t == 0) fm1[bc] = red[0];
        __syncthreads();
        red[t] = mx2; __syncthreads();
        for (int s = 128; s > 0; s >>= 1) { if (t < s) red[t] = fmaxf(red[t], red[t + s]); __syncthreads(); }
        if (t == 0) fm2[bc] = red[0];
        __syncthreads();
        red[t] = mx4; __syncthreads();
        for (int s = 128; s > 0; s >>= 1) { if (t < s) red[t] = fmaxf(red[t], red[t + s]); __syncthreads(); }
        if (t == 0) fm4[bc] = red[0];
        __syncthreads();
        red[t] = mx8; __syncthreads();
        for (int s = 128; s > 0; s >>= 1) { if (t < s) red[t] = fmaxf(red[t], red[t + s]); __syncthreads(); }
        if (t == 0) fm8[bc] = red[0];
    }
}

// ---------------------------------------------------------------------------
// K2: channel-gate MLP
// ---------------------------------------------------------------------------
__global__ __launch_bounds__(256) void k2_gate(
    const float* __restrict__ featA, const float* __restrict__ fm1,
    const float* __restrict__ fm2, const float* __restrict__ fm4, const float* __restrict__ fm8,
    const float* __restrict__ W1, const float* __restrict__ b1,
    const float* __restrict__ W2, const float* __restrict__ b2,
    float* __restrict__ g)
{
    __shared__ float sf[5][256];
    __shared__ float sh[5][16];
    __shared__ float hs[16];
    const int b = blockIdx.x, t = threadIdx.x;
    sf[0][t] = featA[b * 256 + t];
    sf[1][t] = fm1[b * 256 + t];
    sf[2][t] = fm2[b * 256 + t];
    sf[3][t] = fm4[b * 256 + t];
    sf[4][t] = fm8[b * 256 + t];
    __syncthreads();
    if (t < 80) {
        int f = t / 16, j = t % 16;
        float a = b1[j];
        for (int c = 0; c < 256; c++) a += sf[f][c] * W1[c * 16 + j];
        sh[f][j] = fmaxf(a, 0.f);
    }
    __syncthreads();
    if (t < 16) hs[t] = 4.f * sh[0][t] + sh[1][t] + sh[2][t] + sh[3][t] + sh[4][t];
    __syncthreads();
    float a = 8.f * b2[t];
    for (int j = 0; j < 16; j++) a += hs[j] * W2[j * 256 + t];
    g[b * 256 + t] = 1.f / (1.f + __expf(-a));
}

// ---------------------------------------------------------------------------
// K3: spatial-gate input (max & mean over 4C multiscale channels of g*x)
// ---------------------------------------------------------------------------
__global__ __launch_bounds__(256) void k3_comp(
    const float* __restrict__ x, const float* __restrict__ bm2,
    const float* __restrict__ bm4, const float* __restrict__ bm8,
    const float* __restrict__ g, float* __restrict__ comp)
{
    __shared__ float sg[256];
    const int b = blockIdx.x >> 4;
    const int pix = ((blockIdx.x & 15) << 8) + threadIdx.x;
    sg[threadIdx.x] = g[(b << 8) + threadIdx.x];
    __syncthreads();
    const int h = pix >> 6, w = pix & 63;
    const int i2 = ((h >> 1) << 5) + (w >> 1);
    const int i4 = ((h >> 2) << 4) + (w >> 2);
    const int i8 = ((h >> 3) << 3) + (w >> 3);
    const float* xb = x + ((size_t)b << 8) * 4096;
    const float* p2 = bm2 + ((size_t)b << 8) * 1024;
    const float* p4 = bm4 + ((size_t)b << 8) * 256;
    const float* p8 = bm8 + ((size_t)b << 8) * 64;
    float mx = -1e30f, sm = 0.f;
    for (int c = 0; c < 256; c++) {
        float gc = sg[c];
        float xv = xb[(size_t)c * 4096 + pix] * gc;
        float v2 = p2[c * 1024 + i2] * gc;
        float v4 = p4[c * 256 + i4] * gc;
        float v8 = p8[c * 64 + i8] * gc;
        mx = fmaxf(fmaxf(mx, xv), fmaxf(fmaxf(v2, v4), v8));
        sm += xv + v2 + v4 + v8;
    }
    comp[((size_t)b * 2) * 4096 + pix] = mx;
    comp[((size_t)b * 2 + 1) * 4096 + pix] = sm * (1.f / 1024.f);
}

// ---------------------------------------------------------------------------
// K4: 7x7 conv (2->1, pad 3, no bias) + BN(eval) + sigmoid -> spg
// ---------------------------------------------------------------------------
__global__ __launch_bounds__(256) void k4_spgate(
    const float* __restrict__ comp, const float* __restrict__ Wsp,
    const float* __restrict__ bn_g, const float* __restrict__ bn_b,
    const float* __restrict__ bn_m, const float* __restrict__ bn_v,
    float* __restrict__ spg)
{
    __shared__ float w[98];
    const int t = threadIdx.x;
    if (t < 98) w[t] = Wsp[t];
    __syncthreads();
    const int b = blockIdx.x >> 4;
    const int pix = ((blockIdx.x & 15) << 8) + t;
    const int h = pix >> 6, wx = pix & 63;
    const float* c0 = comp + (size_t)b * 2 * 4096;
    float acc = 0.f;
    for (int ci = 0; ci < 2; ci++)
        for (int kh = 0; kh < 7; kh++) {
            int hh = h + kh - 3;
            if (hh < 0 || hh >= 64) continue;
            for (int kw = 0; kw < 7; kw++) {
                int wwp = wx + kw - 3;
                if (wwp < 0 || wwp >= 64) continue;
                acc += c0[ci * 4096 + hh * 64 + wwp] * w[ci * 49 + kh * 7 + kw];
            }
        }
    float sc = rsqrtf(bn_v[0] + 1e-5f) * bn_g[0];
    float sp = (acc - bn_m[0]) * sc + bn_b[0];
    spg[b * 4096 + pix] = 1.f / (1.f + __expf(-sp));
}

// ---------------------------------------------------------------------------
// K_WCAST: bf16 copy of W[:,768:1024] rows (q|k|v order) -> WB[320][256]
// ---------------------------------------------------------------------------
__global__ __launch_bounds__(256) void k_wcast(
    const float* __restrict__ Wq, const float* __restrict__ Wk, const float* __restrict__ Wv,
    unsigned short* __restrict__ WB)
{
    const int o = blockIdx.x;
    const int t = threadIdx.x;
    const float* row = (o < 32) ? (Wq + (size_t)o * 1024)
                      : (o < 64) ? (Wk + (size_t)(o - 32) * 1024)
                                 : (Wv + (size_t)(o - 64) * 1024);
    WB[o * 256 + t] = f2bf(row[768 + t]);
}

// ---------------------------------------------------------------------------
// K_X2T: x2 fp32 [b][256 c][4096 n] -> x2T bf16 [b][4096 n][256 c]
// ---------------------------------------------------------------------------
__global__ __launch_bounds__(256) void k_x2t(
    const float* __restrict__ x2, unsigned short* __restrict__ x2T)
{
    __shared__ unsigned short T[64][72];
    const int b = blockIdx.z;
    const int cb = blockIdx.y * 64;
    const int nb = blockIdx.x * 64;
    const int t = threadIdx.x;
    #pragma unroll
    for (int r = 0; r < 16; r++) {
        int cl = (t >> 6) + 4 * r;
        int nl = t & 63;
        float v = x2[((size_t)(b * 256 + cb + cl)) * 4096 + nb + nl];
        T[nl][cl] = f2bf(v);
    }
    __syncthreads();
    #pragma unroll
    for (int pass = 0; pass < 4; pass++) {
        int nl = (t >> 4) + 16 * pass;
        int c4 = (t & 15) * 4;
        uint2 pk;
        pk.x = (unsigned)T[nl][c4] | ((unsigned)T[nl][c4 + 1] << 16);
        pk.y = (unsigned)T[nl][c4 + 2] | ((unsigned)T[nl][c4 + 3] << 16);
        *(uint2*)(x2T + ((size_t)(b * 4096 + nb + nl)) * 256 + cb + c4) = pk;
    }
}

// ---------------------------------------------------------------------------
// K6: fp32 projection GEMM for low-res P2/P4/P8 passes only.
// ---------------------------------------------------------------------------
__global__ __launch_bounds__(256) void k6_gemm(
    const float* __restrict__ Wq, const float* __restrict__ Wk, const float* __restrict__ Wv,
    int col_off, const float* __restrict__ src, int ns,
    float* __restrict__ outp)
{
    __shared__ float At[32][68];
    __shared__ float Bt[32][64];
    const int b = blockIdx.z;
    const int o_base = blockIdx.y * 64;
    const int n_base = blockIdx.x * 64;
    const int t = threadIdx.x;
    const int tn = t >> 4, tm = t & 15;
    const int lk = t & 31, lo8 = t >> 5;
    const int ln = t & 63, lk4 = t >> 6;
    float acc[4][4];
    #pragma unroll
    for (int i = 0; i < 4; i++)
        #pragma unroll
        for (int j = 0; j < 4; j++) acc[i][j] = 0.f;
    for (int k0 = 0; k0 < 256; k0 += 32) {
        __syncthreads();
        #pragma unroll
        for (int r = 0; r < 8; r++) {
            int o = o_base + lo8 + 8 * r;
            const float* wrow = (o < 32) ? (Wq + (size_t)o * 1024)
                              : (o < 64) ? (Wk + (size_t)(o - 32) * 1024)
                                         : (Wv + (size_t)(o - 64) * 1024);
            At[lk][lo8 + 8 * r] = wrow[col_off + k0 + lk];
        }
        #pragma unroll
        for (int r = 0; r < 8; r++)
            Bt[lk4 + 4 * r][ln] = src[((size_t)b * 256 + k0 + lk4 + 4 * r) * ns + n_base + ln];
        __syncthreads();
        #pragma unroll
        for (int kk = 0; kk < 32; kk++) {
            float4 a = *(const float4*)&At[kk][4 * tn];
            float4 bb = *(const float4*)&Bt[kk][4 * tm];
            acc[0][0] += a.x * bb.x; acc[0][1] += a.x * bb.y; acc[0][2] += a.x * bb.z; acc[0][3] += a.x * bb.w;
            acc[1][0] += a.y * bb.x; acc[1][1] += a.y * bb.y; acc[1][2] += a.y * bb.z; acc[1][3] += a.y * bb.w;
            acc[2][0] += a.z * bb.x; acc[2][1] += a.z * bb.y; acc[2][2] += a.z * bb.z; acc[2][3] += a.z * bb.w;
            acc[3][0] += a.w * bb.x; acc[3][1] += a.w * bb.y; acc[3][2] += a.w * bb.z; acc[3][3] += a.w * bb.w;
        }
    }
    #pragma unroll
    for (int i = 0; i < 4; i++)
        #pragma unroll
        for (int j = 0; j < 4; j++)
            outp[((size_t)b * 320 + o_base + 4 * tn + i) * ns + n_base + 4 * tm + j] = acc[i][j];
}

// ---------------------------------------------------------------------------
// K6M: full-res projection via bf16 MFMA (same as R3).
// ---------------------------------------------------------------------------
__global__ __launch_bounds__(256) void k6m(
    const unsigned short* __restrict__ WB, const unsigned short* __restrict__ x2T,
    const float* __restrict__ bq, const float* __restrict__ bk, const float* __restrict__ bv,
    const float* __restrict__ P2, const float* __restrict__ P4, const float* __restrict__ P8,
    unsigned short* __restrict__ qT, unsigned short* __restrict__ kT,
    unsigned short* __restrict__ vB)
{
    const int b = blockIdx.z;
    const int obase = blockIdx.y * 64;
    const int nb = blockIdx.x * 128;
    const int t = threadIdx.x;
    const int w_ = t >> 6, lane = t & 63;
    const int quad = lane >> 4, l16 = lane & 15;
    const int nbase = nb + 32 * w_;
    f32x4 acc[4][2];
    #pragma unroll
    for (int ot = 0; ot < 4; ot++)
        #pragma unroll
        for (int nt = 0; nt < 2; nt++) { acc[ot][nt][0] = 0.f; acc[ot][nt][1] = 0.f; acc[ot][nt][2] = 0.f; acc[ot][nt][3] = 0.f; }
    const unsigned short* xb = x2T + ((size_t)b * 4096 + nbase) * 256;
    for (int k0 = 0; k0 < 256; k0 += 32) {
        FRAG af[4], bf[2];
        #pragma unroll
        for (int ot = 0; ot < 4; ot++)
            af[ot].u = *(const uint4*)(WB + (size_t)(obase + 16 * ot + l16) * 256 + k0 + quad * 8);
        #pragma unroll
        for (int nt = 0; nt < 2; nt++)
            bf[nt].u = *(const uint4*)(xb + (size_t)(16 * nt + l16) * 256 + k0 + quad * 8);
        #pragma unroll
        for (int ot = 0; ot < 4; ot++)
            #pragma unroll
            for (int nt = 0; nt < 2; nt++)
                acc[ot][nt] = __builtin_amdgcn_mfma_f32_16x16x32_bf16(af[ot].s, bf[nt].s, acc[ot][nt], 0, 0, 0);
    }
    #pragma unroll
    for (int ot = 0; ot < 4; ot++) {
        #pragma unroll
        for (int nt = 0; nt < 2; nt++) {
            int n = nbase + 16 * nt + l16;
            int h = n >> 6, wx = n & 63;
            int i2 = ((h >> 1) << 5) + (wx >> 1);
            int i4 = ((h >> 2) << 4) + (wx >> 2);
            int i8 = ((h >> 3) << 3) + (wx >> 3);
            float vals[4];
            #pragma unroll
            for (int r = 0; r < 4; r++) {
                int o = obase + 16 * ot + 4 * quad + r;
                float bias = (o < 32) ? bq[o] : (o < 64) ? bk[o - 32] : bv[o - 64];
                size_t ro = (size_t)b * 320 + o;
                vals[r] = acc[ot][nt][r] + bias
                        + P2[ro * 1024 + i2] + P4[ro * 256 + i4] + P8[ro * 64 + i8];
            }
            int o0 = obase + 16 * ot + 4 * quad;
            if (o0 < 64) {
                uint2 pk;
                pk.x = (unsigned)f2bf(vals[0]) | ((unsigned)f2bf(vals[1]) << 16);
                pk.y = (unsigned)f2bf(vals[2]) | ((unsigned)f2bf(vals[3]) << 16);
                if (o0 < 32)
                    *(uint2*)(qT + ((size_t)(b * 4096 + n)) * 32 + o0) = pk;
                else
                    *(uint2*)(kT + ((size_t)(b * 4096 + n)) * 32 + (o0 - 32)) = pk;
            } else {
                #pragma unroll
                for (int r = 0; r < 4; r++)
                    vB[((size_t)(b * 256) + o0 - 64 + r) * 4096 + n] = f2bf(vals[r]);
            }
        }
    }
}

// ---------------------------------------------------------------------------
// K7: MFMA flash attention, in-block KV split. Block = (b, 64-query tile),
// 1024 thr / 16 waves = 4 KV-split groups x 4 waves. NO LDS aliasing:
// loop-phase (PL, salpha) and epilogue (SB, stats) are disjoint arrays
// (57.9 KB total). Epilogue: flash-combine of 4 partial (O,m,l), done as
// 4 sequential 64-channel stripe rounds through SB.
// ---------------------------------------------------------------------------
__global__ __launch_bounds__(1024, 4) void k7_attn(
    const unsigned short* __restrict__ qT, const unsigned short* __restrict__ kT,
    const unsigned short* __restrict__ vB, const float* __restrict__ x2,
    const float* __restrict__ gamma, float* __restrict__ outp)
{
    __shared__ unsigned short PL[4][64][72];   // [group][n][m], stride 72 (16B mult)
    __shared__ float salpha[4][64];
    __shared__ float SB[64][68];               // epilogue stripe buffer
    __shared__ float esm[4][64], esl[4][64], esmx[64], esinv[64];
    const int b = blockIdx.x >> 6;
    const int qbase = (blockIdx.x & 63) << 6;
    const int t = threadIdx.x;
    const int wid = t >> 6, lane = t & 63;
    const int s_ = wid >> 2, w_ = wid & 3;
    const int quad = lane >> 4, l16 = lane & 15;

    FRAG qf;
    qf.u = *(const uint4*)(qT + ((size_t)(b * 4096 + qbase + 16 * w_ + l16)) * 32 + quad * 8);

    f32x4 acc[4][4];
    #pragma unroll
    for (int ct = 0; ct < 4; ct++)
        #pragma unroll
        for (int nt = 0; nt < 4; nt++) { acc[ct][nt][0] = 0.f; acc[ct][nt][1] = 0.f; acc[ct][nt][2] = 0.f; acc[ct][nt][3] = 0.f; }
    float m_run = -1e30f, l_run = 0.f;
    const unsigned short* kTb = kT + (size_t)b * 4096 * 32;
    const unsigned short* vBb = vB + (size_t)b * 256 * 4096;

    for (int j = 0; j < 16; j++) {
        const int mo = (s_ << 10) + (j << 6);
        // --- QK^T: E^T[m][n] for this wave's 16 queries, 64 keys ---
        f32x4 e[4];
        #pragma unroll
        for (int mt = 0; mt < 4; mt++) {
            FRAG kf;
            kf.u = *(const uint4*)(kTb + (size_t)(mo + 16 * mt + l16) * 32 + quad * 8);
            f32x4 z; z[0] = 0.f; z[1] = 0.f; z[2] = 0.f; z[3] = 0.f;
            e[mt] = __builtin_amdgcn_mfma_f32_16x16x32_bf16(kf.s, qf.s, z, 0, 0, 0);
        }
        // --- online softmax (per lane-column n = 16w+l16) ---
        float pmax = e[0][0];
        #pragma unroll
        for (int mt = 0; mt < 4; mt++)
            #pragma unroll
            for (int r = 0; r < 4; r++) pmax = fmaxf(pmax, e[mt][r]);
        pmax = fmaxf(pmax, __shfl_xor(pmax, 16));
        pmax = fmaxf(pmax, __shfl_xor(pmax, 32));
        float mnew = fmaxf(m_run, pmax);
        float alpha = __expf(m_run - mnew);
        m_run = mnew;
        float ps = 0.f;
        uint2 pk[4];
        #pragma unroll
        for (int mt = 0; mt < 4; mt++) {
            union { float f; unsigned int u; } p0, p1, p2, p3;
            p0.f = __expf(e[mt][0] - mnew);
            p1.f = __expf(e[mt][1] - mnew);
            p2.f = __expf(e[mt][2] - mnew);
            p3.f = __expf(e[mt][3] - mnew);
            ps += p0.f + p1.f + p2.f + p3.f;
            pk[mt].x = __builtin_amdgcn_perm(p1.u, p0.u, 0x07060302u);
            pk[mt].y = __builtin_amdgcn_perm(p3.u, p2.u, 0x07060302u);
        }
        l_run = l_run * alpha + ps;
        __syncthreads();   // previous iteration's PV reads of PL/salpha done
        #pragma unroll
        for (int mt = 0; mt < 4; mt++)
            *(uint2*)&PL[s_][16 * w_ + l16][16 * mt + 4 * quad] = pk[mt];
        if (quad == 0) salpha[s_][16 * w_ + l16] = alpha;
        __syncthreads();   // PL/salpha visible
        // --- rescale O by alpha(n) ---
        float al[4];
        #pragma unroll
        for (int nt = 0; nt < 4; nt++) al[nt] = salpha[s_][16 * nt + l16];
        #pragma unroll
        for (int ct = 0; ct < 4; ct++)
            #pragma unroll
            for (int nt = 0; nt < 4; nt++) acc[ct][nt] *= al[nt];
        // --- PV: O[c][n] += V[c][m] * P^T[m][n] ---
        #pragma unroll
        for (int kh = 0; kh < 2; kh++) {
            FRAG av[4], bp[4];
            #pragma unroll
            for (int ct = 0; ct < 4; ct++)
                av[ct].u = *(const uint4*)(vBb + (size_t)(64 * w_ + 16 * ct + l16) * 4096
                                           + mo + 32 * kh + quad * 8);
            #pragma unroll
            for (int nt = 0; nt < 4; nt++)
                bp[nt].u = *(const uint4*)&PL[s_][16 * nt + l16][32 * kh + quad * 8];
            #pragma unroll
            for (int ct = 0; ct < 4; ct++)
                #pragma unroll
                for (int nt = 0; nt < 4; nt++)
                    acc[ct][nt] = __builtin_amdgcn_mfma_f32_16x16x32_bf16(av[ct].s, bp[nt].s, acc[ct][nt], 0, 0, 0);
        }
    }
    // --- epilogue: per-group (m,l) -> stats (disjoint LDS, no aliasing) ---
    float lt = l_run + __shfl_xor(l_run, 16);
    lt += __shfl_xor(lt, 32);
    if (quad == 0) { esm[s_][16 * w_ + l16] = m_run; esl[s_][16 * w_ + l16] = lt; }
    __syncthreads();
    if (t < 64) {
        float m0 = esm[0][t], m1 = esm[1][t], m2 = esm[2][t], m3 = esm[3][t];
        float mxx = fmaxf(fmaxf(m0, m1), fmaxf(m2, m3));
        float l = esl[0][t] * __expf(m0 - mxx) + esl[1][t] * __expf(m1 - mxx)
                + esl[2][t] * __expf(m2 - mxx) + esl[3][t] * __expf(m3 - mxx);
        esmx[t] = mxx; esinv[t] = 1.f / l;
    }
    __syncthreads();
    float f[4];
    #pragma unroll
    for (int nt = 0; nt < 4; nt++) {
        int n = 16 * nt + l16;
        f[nt] = __expf(esm[s_][n] - esmx[n]);
    }
    const float gm = gamma[0];
    // --- combine: 4 c-stripe rounds; group sr's wave w_==cs adds its acc ---
    for (int cs = 0; cs < 4; cs++) {
        for (int sr = 0; sr < 4; sr++) {
            if (s_ == sr && w_ == cs) {
                #pragma unroll
                for (int ct = 0; ct < 4; ct++)
                    #pragma unroll
                    for (int nt = 0; nt < 4; nt++)
                        #pragma unroll
                        for (int r = 0; r < 4; r++) {
                            int cl = 16 * ct + 4 * quad + r;
                            int n = 16 * nt + l16;
                            float v = acc[ct][nt][r] * f[nt];
                            if (sr == 0) SB[cl][n] = v;
                            else         SB[cl][n] += v;
                        }
            }
            __syncthreads();
        }
        // all 1024 threads write out stripe cs: c in [64cs, 64cs+64)
        {
            int cl = t >> 4;
            int n4 = (t & 15) * 4;
            float4 vv = *(float4*)&SB[cl][n4];
            int c = 64 * cs + cl;
            size_t idx = ((size_t)b * 256 + c) * 4096 + qbase + n4;
            float4 xv = *(const float4*)(x2 + idx);
            float4 ov;
            ov.x = gm * vv.x * esinv[n4]     + xv.x;
            ov.y = gm * vv.y * esinv[n4 + 1] + xv.y;
            ov.z = gm * vv.z * esinv[n4 + 2] + xv.z;
            ov.w = gm * vv.w * esinv[n4 + 3] + xv.w;
            *(float4*)(outp + idx) = ov;
        }
        __syncthreads();   // SB reuse next stripe
    }
}

// ---------------------------------------------------------------------------
extern "C" void kernel_launch(void* const* d_in, const int* in_sizes, int n_in,
                              void* d_out, int out_size, void* d_ws, size_t ws_size,
                              hipStream_t stream) {
    (void)in_sizes; (void)n_in; (void)out_size; (void)ws_size;
    const float* x    = (const float*)d_in[0];
    const float* W1   = (const float*)d_in[1];
    const float* b1   = (const float*)d_in[2];
    const float* W2   = (const float*)d_in[3];
    const float* b2   = (const float*)d_in[4];
    const float* Wq   = (const float*)d_in[5];
    const float* bq   = (const float*)d_in[6];
    const float* Wk   = (const float*)d_in[7];
    const float* bk   = (const float*)d_in[8];
    const float* Wv   = (const float*)d_in[9];
    const float* bv   = (const float*)d_in[10];
    const float* gam  = (const float*)d_in[11];
    const float* Wsp  = (const float*)d_in[12];
    const float* bn_g = (const float*)d_in[13];
    const float* bn_b = (const float*)d_in[14];
    const float* bn_m = (const float*)d_in[15];
    const float* bn_v = (const float*)d_in[16];

    float* ws = (float*)d_ws;
    float* bm2   = ws; ws += (size_t)4 * 256 * 1024;
    float* bm4   = ws; ws += (size_t)4 * 256 * 256;
    float* bm8   = ws; ws += (size_t)4 * 256 * 64;
    float* featA = ws; ws += 1024;
    float* fm1   = ws; ws += 1024;
    float* fm2   = ws; ws += 1024;
    float* fm4   = ws; ws += 1024;
    float* fm8   = ws; ws += 1024;
    float* g     = ws; ws += 1024;
    float* comp  = ws; ws += (size_t)4 * 2 * 4096;
    float* spg   = ws; ws += (size_t)4 * 4096;
    float* x2    = ws; ws += (size_t)4 * 256 * 4096;
    float* bm2b  = ws; ws += (size_t)4 * 256 * 1024;
    float* bm4b  = ws; ws += (size_t)4 * 256 * 256;
    float* bm8b  = ws; ws += (size_t)4 * 256 * 64;
    float* P2    = ws; ws += (size_t)4 * 320 * 1024;
    float* P4    = ws; ws += (size_t)4 * 320 * 256;
    float* P8    = ws; ws += (size_t)4 * 320 * 64;
    unsigned short* qT  = (unsigned short*)ws; ws += (size_t)4 * 4096 * 32 / 2;
    unsigned short* kT  = (unsigned short*)ws; ws += (size_t)4 * 4096 * 32 / 2;
    unsigned short* vB  = (unsigned short*)ws; ws += (size_t)4 * 256 * 4096 / 2;
    unsigned short* x2T = (unsigned short*)ws; ws += (size_t)4 * 4096 * 256 / 2;
    unsigned short* WB  = (unsigned short*)ws; ws += (size_t)320 * 256 / 2;

    // Weight cast (no deps)
    k_wcast<<<320, 256, 0, stream>>>(Wq, Wk, Wv, WB);
    // Stage 1: channel gate
    k_pyramid<<<1024, 256, 0, stream>>>(x, nullptr, nullptr, nullptr,
                                        bm2, bm4, bm8, featA, fm1, fm2, fm4, fm8, 0);
    k2_gate<<<4, 256, 0, stream>>>(featA, fm1, fm2, fm4, fm8, W1, b1, W2, b2, g);
    // Stage 2: spatial gate
    k3_comp<<<64, 256, 0, stream>>>(x, bm2, bm4, bm8, g, comp);
    k4_spgate<<<64, 256, 0, stream>>>(comp, Wsp, bn_g, bn_b, bn_m, bn_v, spg);
    k_pyramid<<<1024, 256, 0, stream>>>(x, g, spg, x2,
                                        bm2b, bm4b, bm8b,
                                        nullptr, nullptr, nullptr, nullptr, nullptr, 1);
    // x2 -> bf16 transposed [n][c]
    k_x2t<<<dim3(64, 4, 4), 256, 0, stream>>>(x2, x2T);
    // Stage 3: q/k/v projections, multiscale-decomposed
    k6_gemm<<<dim3(16, 5, 4), 256, 0, stream>>>(Wq, Wk, Wv, 0,   bm2b, 1024, P2);
    k6_gemm<<<dim3(4, 5, 4), 256, 0, stream>>>(Wq, Wk, Wv, 256, bm4b, 256,  P4);
    k6_gemm<<<dim3(1, 5, 4), 256, 0, stream>>>(Wq, Wk, Wv, 512, bm8b, 64,   P8);
    k6m<<<dim3(32, 5, 4), 256, 0, stream>>>(WB, x2T, bq, bk, bv, P2, P4, P8, qT, kT, vB);
    // MFMA flash attention + residual
    k7_attn<<<256, 1024, 0, stream>>>(qT, kT, vB, x2, gam, (float*)d_out);
}